// Round 7
// baseline (33.690 us; speedup 1.0000x reference)
//
#include <hip/hip_runtime.h>

#define BB 4
#define NTOK 2048
#define E 96
#define NH 6
#define DH 16
#define E3 288
#define MSZ (NH*DH*DH)     // 1536 floats per batch
#define SCALE 0.25f        // D^-0.5

// kvT float index: column c (0..191), row n (0..31); stride 36, XOR swizzle on n.
__device__ __forceinline__ int KT4(int c, int nc) {
    return c * 36 + (nc ^ ((c & 7) << 2));
}

// One fused kernel, 256 blocks x 256 threads, 1 block/CU.
// LDS pool layout (float4 units, total 9632 f4 = 150.5 KB):
//   [0,800)      xs    : x tile 32x96 (stride 100 floats); later t2 tile
//   [800,5504)   wkvR  : Wk|Wv 96x192 (stride 196); later scratch/qs/Ms
//   [5504,7232)  kvT   : 192x36 floats, swizzled col-major kv
//   [7232,9632)  wbuf  : 96x96 (stride 100): Wq, then Wff
__global__ __launch_bounds__(256) void k_fused(const float* __restrict__ x,
                                               const float* __restrict__ Wqkv,
                                               const float* __restrict__ bqkv,
                                               const float* __restrict__ Wff,
                                               const float* __restrict__ bff,
                                               float* __restrict__ Mg,
                                               unsigned int* __restrict__ cnt,
                                               float* __restrict__ out) {
    const int b = blockIdx.x >> 6, tile = blockIdx.x & 63;
    const int n0 = tile * 32;
    const int t = threadIdx.x;

    __shared__ float4 smem[9632];
    float4* xs4   = smem;                 float* xs  = (float*)xs4;
    float4* wkv4  = smem + 800;
    float4* kvT4  = smem + 5504;          float* kvT = (float*)kvT4;
    float4* wbuf4 = smem + 7232;
    // overlays inside wkvR (floats relative to wkv4):
    float4* scratch = wkv4;                          // f4 [0,2304)
    float*  qs  = (float*)wkv4 + 9216;               // floats [9216,12416)
    float*  Ms2 = (float*)wkv4 + 12416;              // floats [12416,14336)

    // ---------------- Phase 1: stage x, Wkv, Wq ----------------
    {
        const float4* src = (const float4*)(x + ((size_t)b * NTOK + n0) * E);
        for (int f = t; f < 768; f += 256) xs4[(f / 24) * 25 + (f % 24)] = src[f];
    }
    {
        const float4* src = (const float4*)Wqkv;
#pragma unroll
        for (int i = 0; i < 18; i++) {            // Wk|Wv cols 96..287
            int f = t + i * 256;
            int e = f / 48, c = f % 48;
            wkv4[e * 49 + c] = src[e * 72 + 24 + c];
        }
#pragma unroll
        for (int i = 0; i < 9; i++) {             // Wq cols 0..95
            int f = t + i * 256;
            int e = f / 24, c = f % 24;
            wbuf4[e * 25 + c] = src[e * 72 + c];
        }
    }
    __syncthreads();

    // ---------------- Phase 2: kv = x@[Wk|Wv] (es-split-2) ----------------
    {
        const int es = t >> 7;
        const int tt = t & 127;
        const int rg = tt >> 4, cg = tt & 15;
        const int r0 = rg * 4, c0 = cg * 12;
        float acc[4][12];
#pragma unroll
        for (int i = 0; i < 4; i++)
#pragma unroll
            for (int j = 0; j < 12; j++) acc[i][j] = 0.f;

#pragma unroll
        for (int ch = 0; ch < 6; ch++) {
            const int e0 = es * 48 + ch * 8;
            float4 xr[4][2];
#pragma unroll
            for (int i = 0; i < 4; i++) {
                xr[i][0] = *(const float4*)&xs[(r0 + i) * 100 + e0];
                xr[i][1] = *(const float4*)&xs[(r0 + i) * 100 + e0 + 4];
            }
#pragma unroll
            for (int ee = 0; ee < 8; ee++) {
                const int e = e0 + ee;
                float w[12];
                *(float4*)&w[0] = wkv4[e * 49 + 3 * cg];
                *(float4*)&w[4] = wkv4[e * 49 + 3 * cg + 1];
                *(float4*)&w[8] = wkv4[e * 49 + 3 * cg + 2];
#pragma unroll
                for (int i = 0; i < 4; i++) {
                    const float xv = ((const float*)&xr[i][ee >> 2])[ee & 3];
#pragma unroll
                    for (int j = 0; j < 12; j++) acc[i][j] += xv * w[j];
                }
            }
        }
        __syncthreads();              // wkv weight reads done -> scratch reuse

        if (es == 1) {
#pragma unroll
            for (int i = 0; i < 4; i++)
#pragma unroll
                for (int q = 0; q < 3; q++)
                    scratch[(i * 3 + q) * 128 + tt] =
                        make_float4(acc[i][q * 4], acc[i][q * 4 + 1], acc[i][q * 4 + 2], acc[i][q * 4 + 3]);
        }
        __syncthreads();
        if (es == 0) {
            float bb[12];
            *(float4*)&bb[0] = *(const float4*)&bqkv[E + c0];
            *(float4*)&bb[4] = *(const float4*)&bqkv[E + c0 + 4];
            *(float4*)&bb[8] = *(const float4*)&bqkv[E + c0 + 8];
#pragma unroll
            for (int i = 0; i < 4; i++)
#pragma unroll
                for (int q = 0; q < 3; q++) {
                    const float4 o = scratch[(i * 3 + q) * 128 + tt];
                    acc[i][q * 4]     += o.x + bb[q * 4];
                    acc[i][q * 4 + 1] += o.y + bb[q * 4 + 1];
                    acc[i][q * 4 + 2] += o.z + bb[q * 4 + 2];
                    acc[i][q * 4 + 3] += o.w + bb[q * 4 + 3];
                }
#pragma unroll
            for (int j = 0; j < 12; j++) {
                const int c = c0 + j;
                *(float4*)&kvT[KT4(c, r0)] =
                    make_float4(acc[0][j], acc[1][j], acc[2][j], acc[3][j]);
            }
        }
    }
    __syncthreads();

    // ---------------- Phase 3: M partials -> atomics -> publish ----------------
    {
        const int d1 = t >> 4, d2 = t & 15;
        float m[NH] = {0.f, 0.f, 0.f, 0.f, 0.f, 0.f};
#pragma unroll
        for (int nc = 0; nc < 32; nc += 4) {
#pragma unroll
            for (int h = 0; h < NH; h++) {
                const float4 kf = *(const float4*)&kvT[KT4(h * 16 + d1, nc)];
                const float4 vf = *(const float4*)&kvT[KT4(96 + h * 16 + d2, nc)];
                m[h] += kf.x * vf.x + kf.y * vf.y + kf.z * vf.z + kf.w * vf.w;
            }
        }
#pragma unroll
        for (int h = 0; h < NH; h++)
            unsafeAtomicAdd(&Mg[b * MSZ + h * 256 + d1 * 16 + d2], m[h]);
    }
    __syncthreads();
    if (t == 0) { __threadfence(); atomicAdd(&cnt[b], 1u); }

    // ---------------- Phase 4: q = x@Wq (es-split-4), overlap M wait --------
    const int es4 = t >> 6;
    const int tt4 = t & 63;
    const int rg4 = tt4 >> 3, cg4 = tt4 & 7;
    const int r04 = rg4 * 4, c04 = cg4 * 12;
    {
        float acc[4][12];
#pragma unroll
        for (int i = 0; i < 4; i++)
#pragma unroll
            for (int j = 0; j < 12; j++) acc[i][j] = 0.f;
#pragma unroll
        for (int ch = 0; ch < 3; ch++) {
            const int e0 = es4 * 24 + ch * 8;
            float4 xr[4][2];
#pragma unroll
            for (int i = 0; i < 4; i++) {
                xr[i][0] = *(const float4*)&xs[(r04 + i) * 100 + e0];
                xr[i][1] = *(const float4*)&xs[(r04 + i) * 100 + e0 + 4];
            }
#pragma unroll
            for (int ee = 0; ee < 8; ee++) {
                const int e = e0 + ee;
                float w[12];
                *(float4*)&w[0] = wbuf4[e * 25 + 3 * cg4];
                *(float4*)&w[4] = wbuf4[e * 25 + 3 * cg4 + 1];
                *(float4*)&w[8] = wbuf4[e * 25 + 3 * cg4 + 2];
#pragma unroll
                for (int i = 0; i < 4; i++) {
                    const float xv = ((const float*)&xr[i][ee >> 2])[ee & 3];
#pragma unroll
                    for (int j = 0; j < 12; j++) acc[i][j] += xv * w[j];
                }
            }
        }
        __syncthreads();
        if (es4 > 0) {
#pragma unroll
            for (int i = 0; i < 4; i++)
#pragma unroll
                for (int q = 0; q < 3; q++)
                    scratch[(es4 - 1) * 768 + (i * 3 + q) * 64 + tt4] =
                        make_float4(acc[i][q * 4], acc[i][q * 4 + 1], acc[i][q * 4 + 2], acc[i][q * 4 + 3]);
        }
        __syncthreads();
        if (t < 64) {                 // wave0: reduce + bias -> qs
            float bb[12];
            *(float4*)&bb[0] = *(const float4*)&bqkv[c04];
            *(float4*)&bb[4] = *(const float4*)&bqkv[c04 + 4];
            *(float4*)&bb[8] = *(const float4*)&bqkv[c04 + 8];
#pragma unroll
            for (int s = 0; s < 3; s++)
#pragma unroll
                for (int i = 0; i < 4; i++)
#pragma unroll
                    for (int q = 0; q < 3; q++) {
                        const float4 o = scratch[s * 768 + (i * 3 + q) * 64 + tt4];
                        acc[i][q * 4]     += o.x;
                        acc[i][q * 4 + 1] += o.y;
                        acc[i][q * 4 + 2] += o.z;
                        acc[i][q * 4 + 3] += o.w;
                    }
#pragma unroll
            for (int i = 0; i < 4; i++)
#pragma unroll
                for (int q = 0; q < 3; q++)
                    *(float4*)&qs[(r04 + i) * 100 + c04 + q * 4] =
                        make_float4(acc[i][q * 4] + bb[q * 4], acc[i][q * 4 + 1] + bb[q * 4 + 1],
                                    acc[i][q * 4 + 2] + bb[q * 4 + 2], acc[i][q * 4 + 3] + bb[q * 4 + 3]);
        } else {                      // waves 1-3: restage wbuf <- Wff
            const float4* src = (const float4*)Wff;
#pragma unroll
            for (int i = 0; i < 12; i++) {
                int f = (t - 64) + i * 192;
                int e = f / 24, c = f % 24;
                wbuf4[e * 25 + c] = src[e * 24 + c];
            }
            if (t == 255) {           // spinner, overlapped with restage/reduce
                while (__hip_atomic_load(&cnt[b], __ATOMIC_ACQUIRE, __HIP_MEMORY_SCOPE_AGENT) < 64u) {}
            }
        }
    }
    __syncthreads();

    // ---------------- Phase 5: load M (agent scope), scale -> Ms2 ----------
    {
#pragma unroll
        for (int i = 0; i < 6; i++) {
            const int o = t + i * 256;
            const int h = o >> 8, d1 = (o >> 4) & 15, d2 = o & 15;
            Ms2[h * 320 + d2 * 20 + d1] =
                SCALE * __hip_atomic_load(&Mg[b * MSZ + o], __ATOMIC_RELAXED, __HIP_MEMORY_SCOPE_AGENT);
        }
    }
    __syncthreads();

    // ---------------- Phase 6: t2 = q . BD(Ms) -> xs ----------------
    {
        const int r = t >> 3, tc0 = (t & 7) * 12;
        const int h0 = tc0 >> 4, h1 = (tc0 + 11) >> 4;
        float4 qa[4], qb[4];
#pragma unroll
        for (int u = 0; u < 4; u++) {
            qa[u] = *(const float4*)&qs[r * 100 + h0 * 16 + u * 4];
            qb[u] = *(const float4*)&qs[r * 100 + h1 * 16 + u * 4];
        }
        float t2v[12];
#pragma unroll
        for (int j = 0; j < 12; j++) {
            const int c = tc0 + j, h = c >> 4, d2 = c & 15;
            const float4* mrow = (const float4*)&Ms2[h * 320 + d2 * 20];
            float v = 0.f;
#pragma unroll
            for (int u = 0; u < 4; u++) {
                const float4 qv = (h == h0) ? qa[u] : qb[u];
                const float4 mf = mrow[u];
                v += qv.x * mf.x + qv.y * mf.y + qv.z * mf.z + qv.w * mf.w;
            }
            t2v[j] = v;
        }
        __syncthreads();              // x reads fully done; overwrite with t2
#pragma unroll
        for (int q = 0; q < 3; q++)
            *(float4*)&xs[r * 100 + tc0 + q * 4] =
                make_float4(t2v[q * 4], t2v[q * 4 + 1], t2v[q * 4 + 2], t2v[q * 4 + 3]);
    }
    __syncthreads();

    // ---------------- Phase 7: out = t2 @ Wff + bff ----------------
    {
        float acc[4][12];
#pragma unroll
        for (int i = 0; i < 4; i++)
#pragma unroll
            for (int j = 0; j < 12; j++) acc[i][j] = 0.f;
#pragma unroll
        for (int ch = 0; ch < 3; ch++) {
            const int e0 = es4 * 24 + ch * 8;
            float4 xr[4][2];
#pragma unroll
            for (int i = 0; i < 4; i++) {
                xr[i][0] = *(const float4*)&xs[(r04 + i) * 100 + e0];
                xr[i][1] = *(const float4*)&xs[(r04 + i) * 100 + e0 + 4];
            }
#pragma unroll
            for (int ee = 0; ee < 8; ee++) {
                const int e = e0 + ee;
                float w[12];
                *(float4*)&w[0] = wbuf4[e * 25 + 3 * cg4];
                *(float4*)&w[4] = wbuf4[e * 25 + 3 * cg4 + 1];
                *(float4*)&w[8] = wbuf4[e * 25 + 3 * cg4 + 2];
#pragma unroll
                for (int i = 0; i < 4; i++) {
                    const float xv = ((const float*)&xr[i][ee >> 2])[ee & 3];
#pragma unroll
                    for (int j = 0; j < 12; j++) acc[i][j] += xv * w[j];
                }
            }
        }
        __syncthreads();
        if (es4 > 0) {
#pragma unroll
            for (int i = 0; i < 4; i++)
#pragma unroll
                for (int q = 0; q < 3; q++)
                    scratch[(es4 - 1) * 768 + (i * 3 + q) * 64 + tt4] =
                        make_float4(acc[i][q * 4], acc[i][q * 4 + 1], acc[i][q * 4 + 2], acc[i][q * 4 + 3]);
        }
        __syncthreads();
        if (t < 64) {
            float bb[12];
            *(float4*)&bb[0] = *(const float4*)&bff[c04];
            *(float4*)&bb[4] = *(const float4*)&bff[c04 + 4];
            *(float4*)&bb[8] = *(const float4*)&bff[c04 + 8];
#pragma unroll
            for (int s = 0; s < 3; s++)
#pragma unroll
                for (int i = 0; i < 4; i++)
#pragma unroll
                    for (int q = 0; q < 3; q++) {
                        const float4 o = scratch[s * 768 + (i * 3 + q) * 64 + tt4];
                        acc[i][q * 4]     += o.x;
                        acc[i][q * 4 + 1] += o.y;
                        acc[i][q * 4 + 2] += o.z;
                        acc[i][q * 4 + 3] += o.w;
                    }
#pragma unroll
            for (int i = 0; i < 4; i++) {
                float* orow = out + ((size_t)b * NTOK + n0 + r04 + i) * E + c04;
#pragma unroll
                for (int q = 0; q < 3; q++)
                    *(float4*)&orow[q * 4] =
                        make_float4(acc[i][q * 4] + bb[q * 4], acc[i][q * 4 + 1] + bb[q * 4 + 1],
                                    acc[i][q * 4 + 2] + bb[q * 4 + 2], acc[i][q * 4 + 3] + bb[q * 4 + 3]);
            }
        }
    }
}

extern "C" void kernel_launch(void* const* d_in, const int* in_sizes, int n_in,
                              void* d_out, int out_size, void* d_ws, size_t ws_size,
                              hipStream_t stream) {
    const float* x    = (const float*)d_in[0];
    const float* Wqkv = (const float*)d_in[1];
    const float* bqkv = (const float*)d_in[2];
    const float* Wff  = (const float*)d_in[3];
    const float* bff  = (const float*)d_in[4];
    float* out = (float*)d_out;
    float* Mg  = (float*)d_ws;                               // BB*MSZ floats
    unsigned int* cnt = (unsigned int*)(Mg + BB * MSZ);      // BB counters

    hipMemsetAsync(d_ws, 0, (size_t)BB * MSZ * sizeof(float) + BB * sizeof(unsigned int), stream);
    k_fused<<<BB * 64, 256, 0, stream>>>(x, Wqkv, bqkv, Wff, bff, Mg, cnt, out);
}